// Round 4
// baseline (499.474 us; speedup 1.0000x reference)
//
#include <hip/hip_runtime.h>
#include <hip/hip_bf16.h>
#include <cstdint>
#include <cstddef>

typedef unsigned short u16;

static constexpr int Bn = 4, T = 4096, Dm = 1024, H = 16, HDv = 64;
static constexpr int Mrows = Bn * T;     // 16384
static constexpr int Nfused = 3 * Dm;    // 3072
#define EPSV 1e-6f

typedef __attribute__((ext_vector_type(8))) short bf16x8;
typedef __attribute__((ext_vector_type(4))) float f32x4;

#if defined(__has_builtin)
#if __has_builtin(__builtin_amdgcn_global_load_lds)
#define HAS_GLL 1
#endif
#endif
#ifndef HAS_GLL
#define HAS_GLL 0
#endif

__device__ inline float b2f(u16 u) {
  union { unsigned i; float f; } v; v.i = ((unsigned)u) << 16; return v.f;
}
__device__ inline u16 f2b(float f) {
  union { float f; unsigned i; } v; v.f = f;
  unsigned r = (v.i + 0x7fffu + ((v.i >> 16) & 1u)) >> 16;
  return (u16)r;
}

// ---------------- cast fp32 -> bf16 (vectorized) ----------------
__global__ void cast_kernel(const float* __restrict__ in, u16* __restrict__ out, int n4) {
  int i = blockIdx.x * 256 + threadIdx.x;
  if (i >= n4) return;
  float4 v = ((const float4*)in)[i];
  u16 o[4];
  o[0] = f2b(v.x); o[1] = f2b(v.y); o[2] = f2b(v.z); o[3] = f2b(v.w);
  ((uint2*)out)[i] = *(uint2*)o;
}

// ---------------- bf16 GEMM: C = A @ B^T   (A:[M][K], Bm:[N][K], both row stride K) ----
// MODE 1: plain -> bf16 out; MODE 2: +bias -> f32 out; MODE 3: elu+1 iff col<2048 -> bf16
template<int MODE>
__global__ __launch_bounds__(256) void gemm_bt(
    const u16* __restrict__ A, const u16* __restrict__ Bm,
    u16* __restrict__ Cb, float* __restrict__ Cf,
    const float* __restrict__ bias, int Mdim, int N, int K)
{
  __shared__ __align__(16) u16 As[128 * 64];
  __shared__ __align__(16) u16 Bs[128 * 64];
  const int tid  = threadIdx.x;
  const int lane = tid & 63;
  const int wave = tid >> 6;
  const int wr = (wave >> 1) * 64, wc = (wave & 1) * 64;
  const int m0 = blockIdx.x * 128, n0 = blockIdx.y * 128;
  const bool feat = (MODE == 3) && (n0 < 2 * Dm);   // block-uniform (2048 % 128 == 0)

  f32x4 acc[4][4] = {};

  for (int k0 = 0; k0 < K; k0 += 64) {
#pragma unroll
    for (int j = 0; j < 4; ++j) {
      int idx = j * 256 + tid;          // 16B chunk index within 16KB tile
      int row = idx >> 3;
      int col = (idx & 7) << 3;
      const u16* gA = A  + (size_t)(m0 + row) * K + k0 + col;
      const u16* gB = Bm + (size_t)(n0 + row) * K + k0 + col;
#if HAS_GLL
      __builtin_amdgcn_global_load_lds((const __attribute__((address_space(1))) void*)gA,
                                       (__attribute__((address_space(3))) void*)(As + idx * 8), 16, 0, 0);
      __builtin_amdgcn_global_load_lds((const __attribute__((address_space(1))) void*)gB,
                                       (__attribute__((address_space(3))) void*)(Bs + idx * 8), 16, 0, 0);
#else
      *(uint4*)(As + idx * 8) = *(const uint4*)gA;
      *(uint4*)(Bs + idx * 8) = *(const uint4*)gB;
#endif
    }
    __syncthreads();
#pragma unroll
    for (int kk = 0; kk < 64; kk += 32) {
      bf16x8 af[4], bfv[4];
#pragma unroll
      for (int i = 0; i < 4; ++i) {
        af[i]  = *(const bf16x8*)&As[(wr + i * 16 + (lane & 15)) * 64 + kk + (lane >> 4) * 8];
        bfv[i] = *(const bf16x8*)&Bs[(wc + i * 16 + (lane & 15)) * 64 + kk + (lane >> 4) * 8];
      }
#pragma unroll
      for (int i = 0; i < 4; ++i)
#pragma unroll
        for (int j = 0; j < 4; ++j)
          acc[i][j] = __builtin_amdgcn_mfma_f32_16x16x32_bf16(af[i], bfv[j], acc[i][j], 0, 0, 0);
    }
    __syncthreads();
  }

  // epilogue: C/D layout col = lane&15, row = (lane>>4)*4 + r  (m89-verified)
#pragma unroll
  for (int i = 0; i < 4; ++i) {
#pragma unroll
    for (int j = 0; j < 4; ++j) {
#pragma unroll
      for (int r = 0; r < 4; ++r) {
        int row = m0 + wr + i * 16 + (lane >> 4) * 4 + r;
        int col = n0 + wc + j * 16 + (lane & 15);
        float v = acc[i][j][r];
        if (MODE == 2) {
          Cf[(size_t)row * N + col] = v + bias[col];
        } else {
          if (feat) v = (v > 0.f) ? (v + 1.f) : __expf(v);
          Cb[(size_t)row * N + col] = f2b(v);
        }
      }
    }
  }
}

// ---------------- KV = K^T V per (b,h) + K_sum, reduce over T with atomics ----------------
// Kb/Vb point at the K/V columns inside the fused QKV buffer; row stride = ldr.
__global__ __launch_bounds__(256) void kv_kernel(
    const u16* __restrict__ Kb, const u16* __restrict__ Vb, int ldr,
    float* __restrict__ KV, float* __restrict__ Ksum)
{
  const int bh = blockIdx.x;
  const int b = bh >> 4, h = bh & 15;
  const int chunk = blockIdx.y; // 8 chunks of 512 t's
  __shared__ __align__(16) float Ks[32][64];
  __shared__ __align__(16) float Vs[32][64];
  const int tid = threadIdx.x;
  const int dq = tid >> 4, eq = tid & 15; // d0 = dq*4, e0 = eq*4
  float acc[4][4] = {};
  float ksum[4] = {};
  const int srow = tid >> 3, scol = (tid & 7) << 3;

  for (int tile = 0; tile < 16; ++tile) {
    const int t0 = chunk * 512 + tile * 32;
    const u16* gK = Kb + ((size_t)(b * T + t0 + srow)) * ldr + h * HDv + scol;
    const u16* gV = Vb + ((size_t)(b * T + t0 + srow)) * ldr + h * HDv + scol;
    uint4 ku = *(const uint4*)gK;
    uint4 vu = *(const uint4*)gV;
    __syncthreads(); // previous tile fully consumed
    u16* kp = (u16*)&ku; u16* vp = (u16*)&vu;
#pragma unroll
    for (int q = 0; q < 8; ++q) { Ks[srow][scol + q] = b2f(kp[q]); Vs[srow][scol + q] = b2f(vp[q]); }
    __syncthreads();
#pragma unroll
    for (int tt = 0; tt < 32; ++tt) {
      f32x4 kv = *(const f32x4*)&Ks[tt][dq * 4];
      f32x4 vv = *(const f32x4*)&Vs[tt][eq * 4];
#pragma unroll
      for (int i = 0; i < 4; ++i)
#pragma unroll
        for (int j = 0; j < 4; ++j)
          acc[i][j] += kv[i] * vv[j];
    }
#pragma unroll
    for (int s = 0; s < 2; ++s) {
      f32x4 kv = *(const f32x4*)&Ks[eq * 2 + s][dq * 4];
#pragma unroll
      for (int i = 0; i < 4; ++i) ksum[i] += kv[i];
    }
  }
  float* KVp = KV + (size_t)bh * HDv * HDv;
#pragma unroll
  for (int i = 0; i < 4; ++i)
#pragma unroll
    for (int j = 0; j < 4; ++j)
      atomicAdd(&KVp[(dq * 4 + i) * HDv + eq * 4 + j], acc[i][j]);
#pragma unroll
  for (int i = 0; i < 4; ++i) atomicAdd(&Ksum[bh * HDv + dq * 4 + i], ksum[i]);
}

// ---------------- ctx = (Q @ KV) / (Q . Ksum + eps) -> bf16 (stride Dm out) ------------
__global__ __launch_bounds__(256) void ctx_kernel(
    const u16* __restrict__ Qb, int ldr, const float* __restrict__ KV,
    const float* __restrict__ Ksum, u16* __restrict__ ctx)
{
  const int bh = blockIdx.x;
  const int b = bh >> 4, h = bh & 15;
  const int t0 = blockIdx.y * 64;
  __shared__ __align__(16) float KVs[64][64];
  __shared__ __align__(16) float Qs[64][68]; // pad to avoid tq-stride conflicts
  __shared__ float Ksm[64];
  const int tid = threadIdx.x;
  const float* KVg = KV + (size_t)bh * 4096;
#pragma unroll
  for (int j = 0; j < 4; ++j) {
    int idx = j * 256 + tid;
    ((f32x4*)KVs)[idx] = ((const f32x4*)KVg)[idx];
  }
  if (tid < 64) Ksm[tid] = Ksum[bh * HDv + tid];
#pragma unroll
  for (int j = 0; j < 2; ++j) {
    int c = j * 256 + tid;
    int row = c >> 3, col = (c & 7) << 3;
    uint4 qu = *(const uint4*)(Qb + ((size_t)(b * T + t0 + row)) * ldr + h * HDv + col);
    u16* qp = (u16*)&qu;
#pragma unroll
    for (int q = 0; q < 8; ++q) Qs[row][col + q] = b2f(qp[q]);
  }
  __syncthreads();
  const int tq = tid >> 2, e0 = (tid & 3) * 16;
  f32x4 acc[4] = {};
  float z = 0.f;
#pragma unroll
  for (int d = 0; d < 64; ++d) {
    float q = Qs[tq][d];
    z += q * Ksm[d];
#pragma unroll
    for (int j = 0; j < 4; ++j) {
      f32x4 kv = *(const f32x4*)&KVs[d][e0 + j * 4];
      acc[j] += q * kv;
    }
  }
  float inv = 1.f / (z + EPSV);
  u16 o[16];
#pragma unroll
  for (int j = 0; j < 4; ++j)
#pragma unroll
    for (int r = 0; r < 4; ++r) o[j * 4 + r] = f2b(acc[j][r] * inv);
  u16* dst = ctx + ((size_t)(b * T + t0 + tq)) * Dm + h * HDv + e0;
  *(uint4*)dst = *(uint4*)&o[0];
  *(uint4*)(dst + 8) = *(uint4*)&o[8];
}

// ---------------- launch ----------------
extern "C" void kernel_launch(void* const* d_in, const int* in_sizes, int n_in,
                              void* d_out, int out_size, void* d_ws, size_t ws_size,
                              hipStream_t stream)
{
  const float* x  = (const float*)d_in[0];
  const float* Wq = (const float*)d_in[1];
  const float* Wk = (const float*)d_in[2];
  const float* Wv = (const float*)d_in[3];
  const float* Wo = (const float*)d_in[4];
  const float* bo = (const float*)d_in[5];
  float* out = (float*)d_out;

  char* ws = (char*)d_ws;
  size_t off = 0;
  auto alloc = [&](size_t bytes) -> void* {
    void* p = ws + off;
    off += (bytes + 255) & ~(size_t)255;
    return p;
  };
  u16* xb   = (u16*)alloc((size_t)Mrows * Dm * 2);          // 32 MB (reused as ctx)
  u16* Wcat = (u16*)alloc((size_t)Nfused * Dm * 2);         // 6 MB (Wq|Wk|Wv rows)
  u16* Wob  = (u16*)alloc((size_t)Dm * Dm * 2);             // 2 MB
  u16* QKV  = (u16*)alloc((size_t)Mrows * Nfused * 2);      // 96 MB
  float* KV   = (float*)alloc((size_t)Bn * H * HDv * HDv * 4); // 1 MB
  float* Ksum = (float*)alloc((size_t)Bn * H * HDv * 4);       // 16 KB
  u16* ctx = xb; // x consumed after fused QKV projection; reuse

  // casts
  {
    int n4 = Mrows * Dm / 4;
    cast_kernel<<<(n4 + 255) / 256, 256, 0, stream>>>(x, xb, n4);
    int w4 = Dm * Dm / 4;
    cast_kernel<<<(w4 + 255) / 256, 256, 0, stream>>>(Wq, Wcat, w4);
    cast_kernel<<<(w4 + 255) / 256, 256, 0, stream>>>(Wk, Wcat + (size_t)Dm * Dm, w4);
    cast_kernel<<<(w4 + 255) / 256, 256, 0, stream>>>(Wv, Wcat + (size_t)2 * Dm * Dm, w4);
    cast_kernel<<<(w4 + 255) / 256, 256, 0, stream>>>(Wo, Wob, w4);
  }

  // fused QKV projection: [16384][3072] = xb @ Wcat^T, elu+1 on cols < 2048
  gemm_bt<3><<<dim3(Mrows / 128, Nfused / 128), 256, 0, stream>>>(
      xb, Wcat, QKV, nullptr, nullptr, Mrows, Nfused, Dm);

  hipMemsetAsync(KV, 0, ((size_t)Bn * H * HDv * HDv + (size_t)Bn * H * HDv) * 4, stream);

  kv_kernel<<<dim3(Bn * H, 8), 256, 0, stream>>>(QKV + Dm, QKV + 2 * Dm, Nfused, KV, Ksum);
  ctx_kernel<<<dim3(Bn * H, T / 64), 256, 0, stream>>>(QKV, Nfused, KV, Ksum, ctx);

  gemm_bt<2><<<dim3(Mrows / 128, Dm / 128), 256, 0, stream>>>(
      ctx, Wob, nullptr, out, bo, Mrows, Dm, Dm);
}

// Round 11
// 444.628 us; speedup vs baseline: 1.1234x; 1.1234x over previous
//
#include <hip/hip_runtime.h>
#include <hip/hip_bf16.h>
#include <cstdint>
#include <cstddef>

typedef unsigned short u16;

static constexpr int Bn = 4, T = 4096, Dm = 1024, H = 16, HDv = 64;
static constexpr int Mrows = Bn * T;     // 16384
static constexpr int Nfused = 3 * Dm;    // 3072
#define EPSV 1e-6f

typedef __attribute__((ext_vector_type(8))) short bf16x8;
typedef __attribute__((ext_vector_type(4))) float f32x4;

__device__ inline float b2f(u16 u) {
  union { unsigned i; float f; } v; v.i = ((unsigned)u) << 16; return v.f;
}
__device__ inline u16 f2b(float f) {
  union { float f; unsigned i; } v; v.f = f;
  unsigned r = (v.i + 0x7fffu + ((v.i >> 16) & 1u)) >> 16;
  return (u16)r;
}

// ---------------- cast fp32 -> bf16 (vectorized) ----------------
__global__ void cast_kernel(const float* __restrict__ in, u16* __restrict__ out, int n4) {
  int i = blockIdx.x * 256 + threadIdx.x;
  if (i >= n4) return;
  float4 v = ((const float4*)in)[i];
  u16 o[4];
  o[0] = f2b(v.x); o[1] = f2b(v.y); o[2] = f2b(v.z); o[3] = f2b(v.w);
  ((uint2*)out)[i] = *(uint2*)o;
}

// ---------------- bf16 GEMM, ring-3 pipelined: C = A @ B^T ----------------
// A:[M][K], Bm:[N][K] row-major bf16. BM=256, BN=128, BK=64, 8 waves (512 thr).
// Ring of 3 LDS K-tiles (48KB each: A 32KB + B 16KB), prefetch depth 2,
// counted s_waitcnt vmcnt(6) (T4), raw s_barrier (1/tile), XOR-swizzle
// byte^=((row&7)<<4) applied via pre-swizzled global source (T2, m201 rule),
// setprio around MFMA (T5).
// MODE 2: +bias -> f32 out; MODE 3: elu+1 iff col<2048 -> bf16 out
#define RING_TILE 49152            // bytes per ring slot (A 32768 + B 16384)
#define RING_BYTES (3 * RING_TILE)

template<int MODE>
__global__ __launch_bounds__(512) void gemm_bt(
    const u16* __restrict__ A, const u16* __restrict__ Bm,
    u16* __restrict__ Cb, float* __restrict__ Cf,
    const float* __restrict__ bias, int Mdim, int N, int K)
{
  __shared__ __align__(16) u16 lds[RING_BYTES / 2];   // 144 KiB
  const int tid  = threadIdx.x;
  const int lane = tid & 63;
  const int wid  = tid >> 6;
  const int wr = (wid & 3) * 64;          // wave M-offset within 256
  const int wc = (wid >> 2) * 64;         // wave N-offset within 128
  const int m0 = blockIdx.x * 256, n0 = blockIdx.y * 128;
  const bool feat = (MODE == 3) && (n0 < 2 * Dm);   // block-uniform (2048 % 128 == 0)

  f32x4 acc[4][4] = {};
  const int nt = K >> 6;                  // K-tiles of 64

  // stage K-tile t into ring slot at byte offset rb.
  // LDS dest is linear (wave-uniform base + lane*16); the source slot index is
  // XOR-swizzled so that LDS[row][slot] holds G[row][slot ^ (row&7)] — the read
  // side applies the same XOR (involution).
  auto stage = [&](int t, int rb) {
    const int k0 = t << 6;
#pragma unroll
    for (int l = 0; l < 4; ++l) {         // A: 256 rows x 64 cols = 2048 chunks
      int c = l * 512 + tid;
      int r = c >> 3;
      int sl = (c & 7) ^ (r & 7);
      const u16* g = A + (size_t)(m0 + r) * K + k0 + sl * 8;
      __builtin_amdgcn_global_load_lds(
          (const __attribute__((address_space(1))) void*)g,
          (__attribute__((address_space(3))) void*)((char*)lds + rb + c * 16),
          16, 0, 0);
    }
#pragma unroll
    for (int l = 0; l < 2; ++l) {         // B: 128 rows x 64 cols = 1024 chunks
      int c = l * 512 + tid;
      int r = c >> 3;
      int sl = (c & 7) ^ (r & 7);
      const u16* g = Bm + (size_t)(n0 + r) * K + k0 + sl * 8;
      __builtin_amdgcn_global_load_lds(
          (const __attribute__((address_space(1))) void*)g,
          (__attribute__((address_space(3))) void*)((char*)lds + rb + 32768 + c * 16),
          16, 0, 0);
    }
  };

  // prologue: fill pipeline 2 deep (12 loads in flight)
  stage(0, 0);
  if (nt > 1) stage(1, RING_TILE);

  int rb = 0;                             // ring byte base of tile t
  for (int t = 0; t < nt; ++t) {
    // retire stage(t): counted wait — 6 loads (stage t+1) stay in flight
    if (t + 1 < nt) {
      asm volatile("s_waitcnt vmcnt(6)" ::: "memory");
    } else {
      asm volatile("s_waitcnt vmcnt(0)" ::: "memory");
    }
    __builtin_amdgcn_s_barrier();
    asm volatile("" ::: "memory");

    // issue prefetch for tile t+2 into ring[(t+2)%3] (last read at tile t-1,
    // protected by the barrier above)
    if (t + 2 < nt) {
      int rb2 = rb + 2 * RING_TILE;
      if (rb2 >= RING_BYTES) rb2 -= RING_BYTES;
      stage(t + 2, rb2);
    }

    const char* Abase = (const char*)lds + rb;
    const char* Bbase = (const char*)lds + rb + 32768;
#pragma unroll
    for (int ks = 0; ks < 2; ++ks) {
      bf16x8 af[4], bf[4];
      const int cb = ks * 64 + (lane >> 4) * 16;   // byte col within 128B row
#pragma unroll
      for (int i = 0; i < 4; ++i) {
        int ar = wr + i * 16 + (lane & 15);
        af[i] = *(const bf16x8*)(Abase + ar * 128 + (cb ^ ((ar & 7) << 4)));
        int br = wc + i * 16 + (lane & 15);
        bf[i] = *(const bf16x8*)(Bbase + br * 128 + (cb ^ ((br & 7) << 4)));
      }
      __builtin_amdgcn_s_setprio(1);
#pragma unroll
      for (int i = 0; i < 4; ++i)
#pragma unroll
        for (int j = 0; j < 4; ++j)
          acc[i][j] = __builtin_amdgcn_mfma_f32_16x16x32_bf16(af[i], bf[j], acc[i][j], 0, 0, 0);
      __builtin_amdgcn_s_setprio(0);
    }

    rb += RING_TILE;
    if (rb == RING_BYTES) rb = 0;
  }

  // epilogue: C/D layout col = lane&15, row = (lane>>4)*4 + r  (m89-verified)
#pragma unroll
  for (int i = 0; i < 4; ++i) {
#pragma unroll
    for (int j = 0; j < 4; ++j) {
#pragma unroll
      for (int r = 0; r < 4; ++r) {
        int row = m0 + wr + i * 16 + (lane >> 4) * 4 + r;
        int col = n0 + wc + j * 16 + (lane & 15);
        float v = acc[i][j][r];
        if (MODE == 2) {
          Cf[(size_t)row * N + col] = v + bias[col];
        } else {
          if (feat) v = (v > 0.f) ? (v + 1.f) : __expf(v);
          Cb[(size_t)row * N + col] = f2b(v);
        }
      }
    }
  }
}

// ---------------- KV = K^T V per (b,h) + K_sum, reduce over T with atomics ----------------
__global__ __launch_bounds__(256) void kv_kernel(
    const u16* __restrict__ Kb, const u16* __restrict__ Vb, int ldr,
    float* __restrict__ KV, float* __restrict__ Ksum)
{
  const int bh = blockIdx.x;
  const int b = bh >> 4, h = bh & 15;
  const int chunk = blockIdx.y; // 8 chunks of 512 t's
  __shared__ __align__(16) float Ks[32][64];
  __shared__ __align__(16) float Vs[32][64];
  const int tid = threadIdx.x;
  const int dq = tid >> 4, eq = tid & 15;
  float acc[4][4] = {};
  float ksum[4] = {};
  const int srow = tid >> 3, scol = (tid & 7) << 3;

  for (int tile = 0; tile < 16; ++tile) {
    const int t0 = chunk * 512 + tile * 32;
    const u16* gK = Kb + ((size_t)(b * T + t0 + srow)) * ldr + h * HDv + scol;
    const u16* gV = Vb + ((size_t)(b * T + t0 + srow)) * ldr + h * HDv + scol;
    uint4 ku = *(const uint4*)gK;
    uint4 vu = *(const uint4*)gV;
    __syncthreads(); // previous tile fully consumed
    u16* kp = (u16*)&ku; u16* vp = (u16*)&vu;
#pragma unroll
    for (int q = 0; q < 8; ++q) { Ks[srow][scol + q] = b2f(kp[q]); Vs[srow][scol + q] = b2f(vp[q]); }
    __syncthreads();
#pragma unroll
    for (int tt = 0; tt < 32; ++tt) {
      f32x4 kv = *(const f32x4*)&Ks[tt][dq * 4];
      f32x4 vv = *(const f32x4*)&Vs[tt][eq * 4];
#pragma unroll
      for (int i = 0; i < 4; ++i)
#pragma unroll
        for (int j = 0; j < 4; ++j)
          acc[i][j] += kv[i] * vv[j];
    }
#pragma unroll
    for (int s = 0; s < 2; ++s) {
      f32x4 kv = *(const f32x4*)&Ks[eq * 2 + s][dq * 4];
#pragma unroll
      for (int i = 0; i < 4; ++i) ksum[i] += kv[i];
    }
  }
  float* KVp = KV + (size_t)bh * HDv * HDv;
#pragma unroll
  for (int i = 0; i < 4; ++i)
#pragma unroll
    for (int j = 0; j < 4; ++j)
      atomicAdd(&KVp[(dq * 4 + i) * HDv + eq * 4 + j], acc[i][j]);
#pragma unroll
  for (int i = 0; i < 4; ++i) atomicAdd(&Ksum[bh * HDv + dq * 4 + i], ksum[i]);
}

// ---------------- ctx = (Q @ KV) / (Q . Ksum + eps) -> bf16 (stride Dm out) ------------
__global__ __launch_bounds__(256) void ctx_kernel(
    const u16* __restrict__ Qb, int ldr, const float* __restrict__ KV,
    const float* __restrict__ Ksum, u16* __restrict__ ctx)
{
  const int bh = blockIdx.x;
  const int b = bh >> 4, h = bh & 15;
  const int t0 = blockIdx.y * 64;
  __shared__ __align__(16) float KVs[64][64];
  __shared__ __align__(16) float Qs[64][68];
  __shared__ float Ksm[64];
  const int tid = threadIdx.x;
  const float* KVg = KV + (size_t)bh * 4096;
#pragma unroll
  for (int j = 0; j < 4; ++j) {
    int idx = j * 256 + tid;
    ((f32x4*)KVs)[idx] = ((const f32x4*)KVg)[idx];
  }
  if (tid < 64) Ksm[tid] = Ksum[bh * HDv + tid];
#pragma unroll
  for (int j = 0; j < 2; ++j) {
    int c = j * 256 + tid;
    int row = c >> 3, col = (c & 7) << 3;
    uint4 qu = *(const uint4*)(Qb + ((size_t)(b * T + t0 + row)) * ldr + h * HDv + col);
    u16* qp = (u16*)&qu;
#pragma unroll
    for (int q = 0; q < 8; ++q) Qs[row][col + q] = b2f(qp[q]);
  }
  __syncthreads();
  const int tq = tid >> 2, e0 = (tid & 3) * 16;
  f32x4 acc[4] = {};
  float z = 0.f;
#pragma unroll
  for (int d = 0; d < 64; ++d) {
    float q = Qs[tq][d];
    z += q * Ksm[d];
#pragma unroll
    for (int j = 0; j < 4; ++j) {
      f32x4 kv = *(const f32x4*)&KVs[d][e0 + j * 4];
      acc[j] += q * kv;
    }
  }
  float inv = 1.f / (z + EPSV);
  u16 o[16];
#pragma unroll
  for (int j = 0; j < 4; ++j)
#pragma unroll
    for (int r = 0; r < 4; ++r) o[j * 4 + r] = f2b(acc[j][r] * inv);
  u16* dst = ctx + ((size_t)(b * T + t0 + tq)) * Dm + h * HDv + e0;
  *(uint4*)dst = *(uint4*)&o[0];
  *(uint4*)(dst + 8) = *(uint4*)&o[8];
}

// ---------------- launch ----------------
extern "C" void kernel_launch(void* const* d_in, const int* in_sizes, int n_in,
                              void* d_out, int out_size, void* d_ws, size_t ws_size,
                              hipStream_t stream)
{
  const float* x  = (const float*)d_in[0];
  const float* Wq = (const float*)d_in[1];
  const float* Wk = (const float*)d_in[2];
  const float* Wv = (const float*)d_in[3];
  const float* Wo = (const float*)d_in[4];
  const float* bo = (const float*)d_in[5];
  float* out = (float*)d_out;

  char* ws = (char*)d_ws;
  size_t off = 0;
  auto alloc = [&](size_t bytes) -> void* {
    void* p = ws + off;
    off += (bytes + 255) & ~(size_t)255;
    return p;
  };
  u16* xb   = (u16*)alloc((size_t)Mrows * Dm * 2);          // 32 MB (reused as ctx)
  u16* Wcat = (u16*)alloc((size_t)Nfused * Dm * 2);         // 6 MB (Wq|Wk|Wv rows)
  u16* Wob  = (u16*)alloc((size_t)Dm * Dm * 2);             // 2 MB
  u16* QKV  = (u16*)alloc((size_t)Mrows * Nfused * 2);      // 96 MB
  float* KV   = (float*)alloc((size_t)Bn * H * HDv * HDv * 4); // 1 MB
  float* Ksum = (float*)alloc((size_t)Bn * H * HDv * 4);       // 16 KB
  u16* ctx = xb; // x consumed after fused QKV projection; reuse

  // casts
  {
    int n4 = Mrows * Dm / 4;
    cast_kernel<<<(n4 + 255) / 256, 256, 0, stream>>>(x, xb, n4);
    int w4 = Dm * Dm / 4;
    cast_kernel<<<(w4 + 255) / 256, 256, 0, stream>>>(Wq, Wcat, w4);
    cast_kernel<<<(w4 + 255) / 256, 256, 0, stream>>>(Wk, Wcat + (size_t)Dm * Dm, w4);
    cast_kernel<<<(w4 + 255) / 256, 256, 0, stream>>>(Wv, Wcat + (size_t)2 * Dm * Dm, w4);
    cast_kernel<<<(w4 + 255) / 256, 256, 0, stream>>>(Wo, Wob, w4);
  }

  // fused QKV projection: [16384][3072] = xb @ Wcat^T, elu+1 on cols < 2048
  gemm_bt<3><<<dim3(Mrows / 256, Nfused / 128), 512, 0, stream>>>(
      xb, Wcat, QKV, nullptr, nullptr, Mrows, Nfused, Dm);

  hipMemsetAsync(KV, 0, ((size_t)Bn * H * HDv * HDv + (size_t)Bn * H * HDv) * 4, stream);

  kv_kernel<<<dim3(Bn * H, 8), 256, 0, stream>>>(QKV + Dm, QKV + 2 * Dm, Nfused, KV, Ksum);
  ctx_kernel<<<dim3(Bn * H, T / 64), 256, 0, stream>>>(QKV, Nfused, KV, Ksum, ctx);

  gemm_bt<2><<<dim3(Mrows / 256, Dm / 128), 512, 0, stream>>>(
      ctx, Wob, nullptr, out, bo, Mrows, Dm, Dm);
}